// Round 1
// baseline (25.083 us; speedup 1.0000x reference)
//
#include <hip/hip_runtime.h>

// DisplaceChannel: out[b,c,y,x] = in[b,c, y-off_y, x-off_x] (zero outside),
// offsets per channel-group p = c/8:
//   q = p + (p >= 24); ih = q/7 - 3; iw = q%7 - 3; off = (iw*16, ih*16)
// B=16, C=384, H=64, W=64, CP=8, NUM_POS=48, STRIDE=16.
//
// All offsets are multiples of 16 and W=64 -> a float4 along x is entirely
// in- or out-of-bounds and stays 16B-aligned under the shift. One thread per
// float4: one predicated load, one store. Pure memory-bound copy.

#define DC_B 16
#define DC_C 384
#define DC_H 64
#define DC_W 64
#define DC_W4 (DC_W / 4)   // 16 float4 per row
#define DC_TOTAL4 (DC_B * DC_C * DC_H * DC_W4)  // 6,291,456

__global__ __launch_bounds__(256) void displace_kernel(
    const float4* __restrict__ in, float4* __restrict__ out) {
    int t = blockIdx.x * blockDim.x + threadIdx.x;
    if (t >= DC_TOTAL4) return;

    // decode: t = (((b*C + c)*H + y)*W4 + x4)
    int x4   = t & (DC_W4 - 1);        // 0..15
    int rest = t >> 4;
    int y    = rest & (DC_H - 1);      // 0..63
    rest >>= 6;
    int c    = rest % DC_C;            // b not needed separately

    int p  = c >> 3;                   // c / CP
    int q  = p + (p >= 24);            // skip the (0,0) center slot
    int ih = q / 7;                    // 0..6  (compiler emits magic-mul)
    int iw = q - ih * 7;               // 0..6
    int off_y = (ih - 3) * 16;
    int off_x = (iw - 3) * 16;

    int sy = y - off_y;
    int sx = (x4 << 2) - off_x;        // byte-element x of source vector start

    float4 v = make_float4(0.f, 0.f, 0.f, 0.f);
    if ((unsigned)sy < (unsigned)DC_H && (unsigned)sx < (unsigned)DC_W) {
        // source float4 linear index: same (b,c), shifted row/col
        int src = t - off_y * DC_W4 - (off_x >> 2);
        v = in[src];
    }
    out[t] = v;
}

extern "C" void kernel_launch(void* const* d_in, const int* in_sizes, int n_in,
                              void* d_out, int out_size, void* d_ws, size_t ws_size,
                              hipStream_t stream) {
    const float4* in  = (const float4*)d_in[0];
    float4*       out = (float4*)d_out;
    const int threads = 256;
    const int blocks  = (DC_TOTAL4 + threads - 1) / threads;  // 24576
    displace_kernel<<<blocks, threads, 0, stream>>>(in, out);
}

// Round 2
// 24.430 us; speedup vs baseline: 1.0267x; 1.0267x over previous
//
#include <hip/hip_runtime.h>

// DisplaceChannel: out[b,c,y,x] = in[b,c, y-off_y, x-off_x] (zero outside),
// offsets per channel-group p = c/8:
//   q = p + (p >= 24); ih = q/7 - 3; iw = q%7 - 3; off = (iw*16, ih*16)
// B=16, C=384, H=64, W=64, CP=8, NUM_POS=48, STRIDE=16.
//
// All offsets are multiples of 16 and W=64 -> a float4 along x is entirely
// in- or out-of-bounds and stays 16B-aligned under the shift.
//
// R1 -> R2: 4 float4 per thread (y, y+16, y+32, y+48 at fixed x4). Decode
// once, 4 independent predicated loads + 4 stores -> 4x memory-level
// parallelism per thread, 1/4 the waves. Each wave's store op covers 4
// contiguous 1KB row segments (perfect coalescing preserved).

#define DC_B 16
#define DC_C 384
#define DC_H 64
#define DC_W 64
#define DC_W4 (DC_W / 4)                       // 16 float4 per row
#define DC_PLANE4 (DC_H * DC_W4)               // 1024 float4 per (b,c) plane
#define DC_TOTAL4 (DC_B * DC_C * DC_H * DC_W4) // 6,291,456
#define DC_PER_THREAD 4
#define DC_THREADS (DC_TOTAL4 / DC_PER_THREAD) // 1,572,864

__global__ __launch_bounds__(256) void displace_kernel(
    const float4* __restrict__ in, float4* __restrict__ out) {
    int t = blockIdx.x * blockDim.x + threadIdx.x;
    if (t >= DC_THREADS) return;

    // t = ((b*C + c)*16 + y0)*16 + x4 ; actual rows y = y0 + 16k, k=0..3
    int x4   = t & (DC_W4 - 1);        // 0..15
    int y0   = (t >> 4) & 15;          // 0..15
    int rest = t >> 8;                 // b*C + c
    int c    = rest % DC_C;

    int p  = c >> 3;                   // c / CP
    int q  = p + (p >= 24);            // skip the (0,0) center slot
    int ih = q / 7;                    // 0..6 (magic-mul)
    int iw = q - ih * 7;               // 0..6
    int off_y = (ih - 3) * 16;
    int off_x = (iw - 3) * 16;

    int sx = (x4 << 2) - off_x;
    bool sx_ok = (unsigned)sx < (unsigned)DC_W;

    int dst0 = rest * DC_PLANE4 + y0 * DC_W4 + x4;
    int sshift = off_y * DC_W4 + (off_x >> 2);   // src = dst - sshift

    float4 v[DC_PER_THREAD];
    #pragma unroll
    for (int k = 0; k < DC_PER_THREAD; ++k) {
        v[k] = make_float4(0.f, 0.f, 0.f, 0.f);
        int sy = y0 + 16 * k - off_y;
        if (sx_ok && (unsigned)sy < (unsigned)DC_H) {
            v[k] = in[dst0 + k * 16 * DC_W4 - sshift];
        }
    }
    #pragma unroll
    for (int k = 0; k < DC_PER_THREAD; ++k) {
        out[dst0 + k * 16 * DC_W4] = v[k];
    }
}

extern "C" void kernel_launch(void* const* d_in, const int* in_sizes, int n_in,
                              void* d_out, int out_size, void* d_ws, size_t ws_size,
                              hipStream_t stream) {
    const float4* in  = (const float4*)d_in[0];
    float4*       out = (float4*)d_out;
    const int threads = 256;
    const int blocks  = (DC_THREADS + threads - 1) / threads;  // 6144
    displace_kernel<<<blocks, threads, 0, stream>>>(in, out);
}

// Round 3
// 24.028 us; speedup vs baseline: 1.0439x; 1.0167x over previous
//
#include <hip/hip_runtime.h>

// DisplaceChannel: out[b,c,y,x] = in[b,c, y-off_y, x-off_x] (zero outside),
// offsets per channel-group p = c/8:
//   q = p + (p >= 24); ih = q/7 - 3; iw = q%7 - 3; off = (iw*16, ih*16)
// B=16, C=384, H=64, W=64, CP=8, NUM_POS=48, STRIDE=16.
//
// All offsets are multiples of 16 and W=64 -> a float4 along x is entirely
// in- or out-of-bounds and stays 16B-aligned under the shift.
//
// R2 -> R3: non-temporal stores for the output stream (nt: no L2/L3
// allocation). The 100.7 MB/replay output stream otherwise evicts the
// 31.5 MB of live input from L3 between graph replays; NT writes keep the
// input resident (reads become L3 hits) and stream the writes at closer to
// the pure-write ceiling (~7 TB/s, per harness memset). Loads stay cached.

#define DC_B 16
#define DC_C 384
#define DC_H 64
#define DC_W 64
#define DC_W4 (DC_W / 4)                       // 16 float4 per row
#define DC_PLANE4 (DC_H * DC_W4)               // 1024 float4 per (b,c) plane
#define DC_TOTAL4 (DC_B * DC_C * DC_H * DC_W4) // 6,291,456
#define DC_PER_THREAD 4
#define DC_THREADS (DC_TOTAL4 / DC_PER_THREAD) // 1,572,864

typedef float __attribute__((ext_vector_type(4))) f32x4;

__global__ __launch_bounds__(256) void displace_kernel(
    const f32x4* __restrict__ in, f32x4* __restrict__ out) {
    int t = blockIdx.x * blockDim.x + threadIdx.x;
    if (t >= DC_THREADS) return;

    // t = ((b*C + c)*16 + y0)*16 + x4 ; actual rows y = y0 + 16k, k=0..3
    int x4   = t & (DC_W4 - 1);        // 0..15
    int y0   = (t >> 4) & 15;          // 0..15
    int rest = t >> 8;                 // b*C + c  (one (b,c) plane per block)
    int c    = rest % DC_C;

    int p  = c >> 3;                   // c / CP
    int q  = p + (p >= 24);            // skip the (0,0) center slot
    int ih = q / 7;                    // 0..6 (magic-mul)
    int iw = q - ih * 7;               // 0..6
    int off_y = (ih - 3) * 16;
    int off_x = (iw - 3) * 16;

    int sx = (x4 << 2) - off_x;
    bool sx_ok = (unsigned)sx < (unsigned)DC_W;

    int dst0 = rest * DC_PLANE4 + y0 * DC_W4 + x4;
    int sshift = off_y * DC_W4 + (off_x >> 2);   // src = dst - sshift

    f32x4 v[DC_PER_THREAD];
    #pragma unroll
    for (int k = 0; k < DC_PER_THREAD; ++k) {
        v[k] = (f32x4)0.f;
        int sy = y0 + 16 * k - off_y;
        if (sx_ok && (unsigned)sy < (unsigned)DC_H) {
            v[k] = in[dst0 + k * 16 * DC_W4 - sshift];
        }
    }
    #pragma unroll
    for (int k = 0; k < DC_PER_THREAD; ++k) {
        __builtin_nontemporal_store(v[k], out + dst0 + k * 16 * DC_W4);
    }
}

extern "C" void kernel_launch(void* const* d_in, const int* in_sizes, int n_in,
                              void* d_out, int out_size, void* d_ws, size_t ws_size,
                              hipStream_t stream) {
    const f32x4* in  = (const f32x4*)d_in[0];
    f32x4*       out = (f32x4*)d_out;
    const int threads = 256;
    const int blocks  = (DC_THREADS + threads - 1) / threads;  // 6144
    displace_kernel<<<blocks, threads, 0, stream>>>(in, out);
}